// Round 7
// baseline (507.631 us; speedup 1.0000x reference)
//
#include <hip/hip_runtime.h>

// MMoE: B=16384, D=1024, E=8, H=512, T=256, TASKS=3
// R2: 701 us. R3: 593 us (coalesced gates). R4: 521 us (XOR-swizzle LDS).
// R5: 498 us fuse tail. R6/R7: 8-phase GEMM -> REGRESSED 2x; reverted.
// R8: serial combine fusion -> 525. R9: 489 T14-pipelined tower. R10: counted
//     vmcnt tower -> 505 REGRESSED. R11: restore R9 -> 484.9 BEST.
//     Accounting: kernels ~330us; ~155us residual ~ 8 launch gaps (~12us ea).
// R12: merge tower(c) + gemm1(c+1) into one heterogeneous kernel (they are
//     independent: tower reads eoc(c), gemm1 writes h1c already consumed by
//     g2(c)). Tower blocks (384) are VMEM-latency-bound; co-resident gemm1
//     blocks (2048) keep MFMA busy -> tower time hidden (m114 co-schedule).
//     Merged LDS capped 40KB (tower single-buffer Bs) to hold gemm1 occupancy.
//     Last chunk keeps the proven R9 standalone tower. 8 -> 7 launches.
//
// Workspace: fixed 48,594,944 B + Bc*16384 B chunk buffers (Bc adapts).

#define BM 128
#define BN 128
#define BK 64

typedef __attribute__((ext_vector_type(8))) short short8;
typedef __attribute__((ext_vector_type(4))) float floatx4;
typedef __attribute__((ext_vector_type(4))) unsigned short ushortx4;
typedef __attribute__((ext_vector_type(8))) unsigned short ushortx8;

__device__ __forceinline__ unsigned short f32_to_bf16(float f) {
  unsigned int u = __float_as_uint(f);
  u += 0x7fffu + ((u >> 16) & 1u);   // round-to-nearest-even (no NaNs in this net)
  return (unsigned short)(u >> 16);
}
__device__ __forceinline__ float bf16_to_f32(unsigned short h) {
  return __uint_as_float(((unsigned int)h) << 16);
}

__device__ __forceinline__ void async_cp16(const void* g, void* lds) {
  __builtin_amdgcn_global_load_lds(
      (const __attribute__((address_space(1))) void*)g,
      (__attribute__((address_space(3))) void*)lds, 16, 0, 0);
}

// ---------------- all weight prep in one kernel ----------------
__device__ __forceinline__ void transpose_slice(
    const float* __restrict__ in, unsigned short* __restrict__ out,
    int K, int N, float (*tile)[33]) {
  int n0 = blockIdx.x * 32, k0 = blockIdx.y * 32;
  for (int i = threadIdx.y; i < 32; i += 8)
    tile[i][threadIdx.x] = in[(size_t)(k0 + i) * N + n0 + threadIdx.x];
  __syncthreads();
  for (int i = threadIdx.y; i < 32; i += 8)
    out[(size_t)(n0 + i) * K + k0 + threadIdx.x] = f32_to_bf16(tile[threadIdx.x][i]);
}

__global__ void prep_kernel(const float* __restrict__ We1, const float* __restrict__ We2,
                            const float* __restrict__ Wt1, const float* __restrict__ Wg,
                            unsigned short* __restrict__ W1T, unsigned short* __restrict__ W2T,
                            unsigned short* __restrict__ Wt1T, float* __restrict__ WgT) {
  __shared__ float tile[32][33];
  int z = blockIdx.z;
  if (z < 8) {
    transpose_slice(We1 + (size_t)z * 524288, W1T + (size_t)z * 524288, 1024, 512, tile);
  } else if (z < 16) {
    if (blockIdx.y < 16)
      transpose_slice(We2 + (size_t)(z - 8) * 262144, W2T + (size_t)(z - 8) * 262144, 512, 512, tile);
  } else if (z < 19) {
    if (blockIdx.x < 8 && blockIdx.y < 16)
      transpose_slice(Wt1 + (size_t)(z - 16) * 131072, Wt1T + (size_t)(z - 16) * 131072, 512, 256, tile);
  } else {
    if (blockIdx.x < 16 && blockIdx.y < 6) {
      int idx = (blockIdx.y * 16 + blockIdx.x) * 256 + threadIdx.y * 32 + threadIdx.x;
      int t = idx >> 13, r = idx & 8191, e = r >> 10, d = r & 1023;
      WgT[idx] = Wg[t * 8192 + d * 8 + e];
    }
  }
}

// ---------------- gates + x->bf16 (fused; reads x once) ----------------
__global__ __launch_bounds__(256) void gates_cvt_kernel(
    const float* __restrict__ x, const float* __restrict__ WgT,
    const float* __restrict__ bg, float* __restrict__ gout,
    unsigned short* __restrict__ xb) {
  int wave = threadIdx.x >> 6, lane = threadIdx.x & 63;
  int b = blockIdx.x * 4 + wave;
  const float* xr = x + (size_t)b * 1024;
  float xv[16];
#pragma unroll
  for (int j = 0; j < 16; j++) xv[j] = xr[lane + 64 * j];
  unsigned short* xbr = xb + (size_t)b * 1024;
#pragma unroll
  for (int j = 0; j < 16; j++) xbr[lane + 64 * j] = f32_to_bf16(xv[j]);
  float mylogit = 0.f;
#pragma unroll
  for (int te = 0; te < 24; te++) {
    const float* w = WgT + te * 1024;
    float a = 0.f;
#pragma unroll
    for (int j = 0; j < 16; j++) a += xv[j] * w[lane + 64 * j];
#pragma unroll
    for (int off = 32; off > 0; off >>= 1) a += __shfl_xor(a, off, 64);
    if (lane == te) mylogit = a;   // compile-time te -> cndmask, no LDS
  }
  if (lane < 24) {
    int t = lane >> 3, e = lane & 7;
    float logit = mylogit + bg[lane];
    float m = logit;
    m = fmaxf(m, __shfl_xor(m, 4, 64));
    m = fmaxf(m, __shfl_xor(m, 2, 64));
    m = fmaxf(m, __shfl_xor(m, 1, 64));
    float ex = __expf(logit - m);
    float s = ex;
    s += __shfl_xor(s, 4, 64);
    s += __shfl_xor(s, 2, 64);
    s += __shfl_xor(s, 1, 64);
    gout[(size_t)t * 131072 + (size_t)b * 8 + e] = ex / s;
  }
}

// ---------------- m97-style 128x128 bf16 GEMM (proven workhorse) ----------------
__global__ __launch_bounds__(256) void gemm_bt_relu(
    const unsigned short* __restrict__ Abase, long aOffZ, int lda,
    const unsigned short* __restrict__ Bbase, long bOffZ,
    const float* __restrict__ biasBase, int biasOffZ,
    unsigned short* __restrict__ Cbase, long cOffZ, int ldc,
    int K) {
  __shared__ __align__(16) unsigned short As[BM * BK];
  __shared__ __align__(16) unsigned short Bs[BN * BK];
  const int tid = threadIdx.x;
  const int z = blockIdx.z;
  const unsigned short* A = Abase + (size_t)aOffZ * z + (size_t)blockIdx.x * BM * lda;
  const unsigned short* Bt = Bbase + (size_t)bOffZ * z + (size_t)blockIdx.y * BN * K;
  const float* bias = biasBase + (size_t)biasOffZ * z + blockIdx.y * BN;
  unsigned short* C = Cbase + (size_t)cOffZ * z + (size_t)blockIdx.x * BM * ldc + blockIdx.y * BN;

  const int wave = tid >> 6, lane = tid & 63;
  const int wm = (wave >> 1) * 64, wn = (wave & 1) * 64;
  const int lm = lane & 15, lq = lane >> 4;
  const int sw = lm & 7;

  floatx4 acc[4][4] = {};

  const int sr = tid >> 3;
  const int sc = (((tid & 7) ^ (sr & 7)) << 3);

  for (int kt = 0; kt < K; kt += BK) {
#pragma unroll
    for (int i = 0; i < 4; i++)
      async_cp16(A + (size_t)(sr + 32 * i) * lda + kt + sc,
                 (char*)As + i * 4096 + tid * 16);
#pragma unroll
    for (int i = 0; i < 4; i++)
      async_cp16(Bt + (size_t)(sr + 32 * i) * K + kt + sc,
                 (char*)Bs + i * 4096 + tid * 16);
    __syncthreads();
#pragma unroll
    for (int ks = 0; ks < 2; ks++) {
      short8 af[4], bf[4];
      const int ch = ((ks * 4 + lq) ^ sw) << 3;
#pragma unroll
      for (int i = 0; i < 4; i++)
        af[i] = *(const short8*)(As + (wm + 16 * i + lm) * BK + ch);
#pragma unroll
      for (int j = 0; j < 4; j++)
        bf[j] = *(const short8*)(Bs + (wn + 16 * j + lm) * BK + ch);
#pragma unroll
      for (int i = 0; i < 4; i++)
#pragma unroll
        for (int j = 0; j < 4; j++)
          acc[i][j] = __builtin_amdgcn_mfma_f32_16x16x32_bf16(af[i], bf[j], acc[i][j], 0, 0, 0);
    }
    __syncthreads();
  }

#pragma unroll
  for (int i = 0; i < 4; i++) {
    const int row = wm + 16 * i + lq * 4;
#pragma unroll
    for (int j = 0; j < 4; j++) {
      const int col = wn + 16 * j + lm;
      const float bv = bias[col];
#pragma unroll
      for (int v = 0; v < 4; v++) {
        float val = fmaxf(acc[i][j][v] + bv, 0.0f);
        C[(size_t)(row + v) * ldc + col] = f32_to_bf16(val);
      }
    }
  }
}

// ---------------- fused combine+towers, T14-pipelined (R9; standalone for last chunk) ----------------
__global__ __launch_bounds__(256, 2) void tower_fused_kernel(
    const unsigned short* __restrict__ eoc, const float* __restrict__ gates,
    const unsigned short* __restrict__ Wt1T,
    const float* __restrict__ bt1, const float* __restrict__ Wt2,
    const float* __restrict__ bt2, float* __restrict__ out,
    int b0, int Bc) {
  __shared__ __align__(16) unsigned short As[64 * 64];      // 8 KB (reused for partials)
  __shared__ __align__(16) unsigned short Bs[2][256 * 64];  // 2 x 32 KB
  const int tid = threadIdx.x;
  const int mtiles = Bc >> 6;
  const int t = blockIdx.x / mtiles;
  const int xbl = blockIdx.x % mtiles;
  const unsigned short* Bt = Wt1T + (size_t)t * 131072;

  const int wave = tid >> 6, lane = tid & 63;
  const int wn = wave * 64;
  const int lm = lane & 15, lq = lane >> 4;
  const int sw = lm & 7;
  const int sr = tid >> 3;
  const int sc = (((tid & 7) ^ (sr & 7)) << 3);

  floatx4 acc[4][4] = {};

  float gv[2][8];
#pragma unroll
  for (int r = 0; r < 2; r++) {
    const floatx4* gp = (const floatx4*)(
        gates + ((size_t)t * 16384 + b0 + (size_t)xbl * 64 + sr + 32 * r) * 8);
    floatx4 g0 = gp[0], g1 = gp[1];
#pragma unroll
    for (int j = 0; j < 4; j++) { gv[r][j] = g0[j]; gv[r][4 + j] = g1[j]; }
  }

  const unsigned short* eb0 = eoc + ((size_t)(xbl * 64 + sr) * 8) * 512 + sc;
  const unsigned short* eb1 = eoc + ((size_t)(xbl * 64 + sr + 32) * 8) * 512 + sc;

  ushortx8 pv[2][8];

#define STAGE_B_T(buf, kt_) do {                                             \
    _Pragma("unroll") for (int i_ = 0; i_ < 8; ++i_)                         \
      async_cp16(Bt + (size_t)(sr + 32 * i_) * 512 + (kt_) + sc,             \
                 (char*)Bs[buf] + i_ * 4096 + tid * 16); } while (0)

#define LOAD_PV(kt_) do {                                                    \
    _Pragma("unroll") for (int e_ = 0; e_ < 8; ++e_) {                       \
      pv[0][e_] = *(const ushortx8*)(eb0 + (size_t)e_ * 512 + (kt_));        \
      pv[1][e_] = *(const ushortx8*)(eb1 + (size_t)e_ * 512 + (kt_));        \
    } } while (0)

  STAGE_B_T(0, 0);
  LOAD_PV(0);

  for (int kt = 0; kt < 512; kt += 64) {
    const int cur = (kt >> 6) & 1;
#pragma unroll
    for (int r = 0; r < 2; r++) {
      float s[8] = {};
#pragma unroll
      for (int e = 0; e < 8; e++) {
        const float g = gv[r][e];
#pragma unroll
        for (int j = 0; j < 8; j++) s[j] += g * bf16_to_f32(pv[r][e][j]);
      }
      ushortx8 o;
#pragma unroll
      for (int j = 0; j < 8; j++) o[j] = f32_to_bf16(s[j]);
      *(ushortx8*)((char*)As + r * 4096 + tid * 16) = o;
    }
    __syncthreads();
    if (kt < 448) {
      STAGE_B_T(cur ^ 1, kt + 64);
      LOAD_PV(kt + 64);
    }
#pragma unroll
    for (int ks = 0; ks < 2; ks++) {
      short8 af[4], bf[4];
      const int ch = ((ks * 4 + lq) ^ sw) << 3;
#pragma unroll
      for (int i = 0; i < 4; i++)
        af[i] = *(const short8*)(As + (16 * i + lm) * 64 + ch);
#pragma unroll
      for (int j = 0; j < 4; j++)
        bf[j] = *(const short8*)(Bs[cur] + (wn + 16 * j + lm) * 64 + ch);
#pragma unroll
      for (int i = 0; i < 4; i++)
#pragma unroll
        for (int j = 0; j < 4; j++)
          acc[i][j] = __builtin_amdgcn_mfma_f32_16x16x32_bf16(af[i], bf[j], acc[i][j], 0, 0, 0);
    }
    __builtin_amdgcn_sched_barrier(0);
    __builtin_amdgcn_s_barrier();
    __builtin_amdgcn_sched_barrier(0);
  }

  float b1v[4], w2v[4];
#pragma unroll
  for (int j = 0; j < 4; j++) {
    int col = wn + 16 * j + lm;
    b1v[j] = bt1[t * 256 + col];
    w2v[j] = Wt2[t * 256 + col];
  }
  float* pt = (float*)As;
#pragma unroll
  for (int i = 0; i < 4; i++) {
#pragma unroll
    for (int v = 0; v < 4; v++) {
      float p = 0.f;
#pragma unroll
      for (int j = 0; j < 4; j++)
        p += fmaxf(acc[i][j][v] + b1v[j], 0.0f) * w2v[j];
      p += __shfl_xor(p, 1, 64);
      p += __shfl_xor(p, 2, 64);
      p += __shfl_xor(p, 4, 64);
      p += __shfl_xor(p, 8, 64);
      if (lm == 0) pt[(16 * i + lq * 4 + v) * 4 + wave] = p;
    }
  }
  __syncthreads();
  if (tid < 64) {
    float s = pt[tid * 4] + pt[tid * 4 + 1] + pt[tid * 4 + 2] + pt[tid * 4 + 3] + bt2[t];
    out[(t << 14) + b0 + xbl * 64 + tid] = 1.f / (1.f + __expf(-s));
  }
}

// ---------------- merged: tower(c) [blocks 0..TB) + gemm1(c+1) [blocks TB..) ----------------
// Independent work co-resident on the CUs: tower blocks are VMEM-latency-bound,
// gemm1 blocks MFMA-bound -> tower hides under gemm1 (m114). LDS capped 40KB
// (tower single-buffer Bs; serial latency hidden by co-residency). gemm1 math
// byte-identical to gemm_bt_relu with (lda=1024,K=1024,bOffZ=524288,
// biasOffZ=512,cOffZ=512,ldc=4096).
__global__ __launch_bounds__(256) void tower_gemm1_kernel(
    const unsigned short* __restrict__ eoc, const float* __restrict__ gates,
    const unsigned short* __restrict__ Wt1T,
    const float* __restrict__ bt1, const float* __restrict__ Wt2,
    const float* __restrict__ bt2, float* __restrict__ out,
    int b0, int Bc,
    const unsigned short* __restrict__ xbn, const unsigned short* __restrict__ W1T,
    const float* __restrict__ be1, unsigned short* __restrict__ h1c) {
  __shared__ __align__(16) unsigned short shmem[20480];   // 40 KB shared by both roles
  const int tid = threadIdx.x;
  const int TB = 3 * (Bc >> 6);
  const int wave = tid >> 6, lane = tid & 63;
  const int lm = lane & 15, lq = lane >> 4;
  const int sw = lm & 7;
  const int sr = tid >> 3;
  const int sc = (((tid & 7) ^ (sr & 7)) << 3);

  if ((int)blockIdx.x < TB) {
    // ---------------- tower role (single-buffered Bs; 40KB) ----------------
    unsigned short* Ast = shmem;            // 4096 el = 8KB
    unsigned short* Bst = shmem + 4096;     // 16384 el = 32KB
    const int mtiles = Bc >> 6;
    const int t = blockIdx.x / mtiles;
    const int xbl = blockIdx.x % mtiles;
    const unsigned short* Bt = Wt1T + (size_t)t * 131072;
    const int wn = wave * 64;

    floatx4 acc[4][4] = {};

    float gv[2][8];
#pragma unroll
    for (int r = 0; r < 2; r++) {
      const floatx4* gp = (const floatx4*)(
          gates + ((size_t)t * 16384 + b0 + (size_t)xbl * 64 + sr + 32 * r) * 8);
      floatx4 g0 = gp[0], g1 = gp[1];
#pragma unroll
      for (int j = 0; j < 4; j++) { gv[r][j] = g0[j]; gv[r][4 + j] = g1[j]; }
    }

    const unsigned short* eb0 = eoc + ((size_t)(xbl * 64 + sr) * 8) * 512 + sc;
    const unsigned short* eb1 = eoc + ((size_t)(xbl * 64 + sr + 32) * 8) * 512 + sc;

    for (int kt = 0; kt < 512; kt += 64) {
      // issue B stage first (async), then pv loads; combine waits pv only
#pragma unroll
      for (int i_ = 0; i_ < 8; ++i_)
        async_cp16(Bt + (size_t)(sr + 32 * i_) * 512 + kt + sc,
                   (char*)Bst + i_ * 4096 + tid * 16);
#pragma unroll
      for (int r = 0; r < 2; r++) {
        const unsigned short* eb = r ? eb1 : eb0;
        float s[8] = {};
#pragma unroll
        for (int e = 0; e < 8; e++) {
          ushortx8 v = *(const ushortx8*)(eb + (size_t)e * 512 + kt);
          const float g = gv[r][e];
#pragma unroll
          for (int j = 0; j < 8; j++) s[j] += g * bf16_to_f32(v[j]);
        }
        ushortx8 o;
#pragma unroll
        for (int j = 0; j < 8; j++) o[j] = f32_to_bf16(s[j]);
        *(ushortx8*)((char*)Ast + r * 4096 + tid * 16) = o;
      }
      __syncthreads();   // drains B stage + As writes
#pragma unroll
      for (int ks = 0; ks < 2; ks++) {
        short8 af[4], bf[4];
        const int ch = ((ks * 4 + lq) ^ sw) << 3;
#pragma unroll
        for (int i = 0; i < 4; i++)
          af[i] = *(const short8*)(Ast + (16 * i + lm) * 64 + ch);
#pragma unroll
        for (int j = 0; j < 4; j++)
          bf[j] = *(const short8*)(Bst + (wn + 16 * j + lm) * 64 + ch);
#pragma unroll
        for (int i = 0; i < 4; i++)
#pragma unroll
          for (int j = 0; j < 4; j++)
            acc[i][j] = __builtin_amdgcn_mfma_f32_16x16x32_bf16(af[i], bf[j], acc[i][j], 0, 0, 0);
      }
      __syncthreads();   // protect LDS reuse
    }

    float b1v[4], w2v[4];
#pragma unroll
    for (int j = 0; j < 4; j++) {
      int col = wn + 16 * j + lm;
      b1v[j] = bt1[t * 256 + col];
      w2v[j] = Wt2[t * 256 + col];
    }
    float* pt = (float*)Ast;
#pragma unroll
    for (int i = 0; i < 4; i++) {
#pragma unroll
      for (int v = 0; v < 4; v++) {
        float p = 0.f;
#pragma unroll
        for (int j = 0; j < 4; j++)
          p += fmaxf(acc[i][j][v] + b1v[j], 0.0f) * w2v[j];
        p += __shfl_xor(p, 1, 64);
        p += __shfl_xor(p, 2, 64);
        p += __shfl_xor(p, 4, 64);
        p += __shfl_xor(p, 8, 64);
        if (lm == 0) pt[(16 * i + lq * 4 + v) * 4 + wave] = p;
      }
    }
    __syncthreads();
    if (tid < 64) {
      float s = pt[tid * 4] + pt[tid * 4 + 1] + pt[tid * 4 + 2] + pt[tid * 4 + 3] + bt2[t];
      out[(t << 14) + b0 + xbl * 64 + tid] = 1.f / (1.f + __expf(-s));
    }
  } else {
    // ---------------- gemm1 role (chunk c+1): h1c = relu(xbn @ We1^T + be1) ----------------
    unsigned short* As = shmem;             // 8192 el = 16KB
    unsigned short* Bs = shmem + 8192;      // 8192 el = 16KB
    const int rb = blockIdx.x - TB;
    const int nbx = Bc >> 7;
    const int bx = rb % nbx;
    const int by = (rb / nbx) & 3;
    const int bz = rb / (nbx * 4);
    const unsigned short* A = xbn + (size_t)bx * BM * 1024;
    const unsigned short* Bt = W1T + (size_t)bz * 524288 + (size_t)by * BN * 1024;
    const float* bias = be1 + bz * 512 + by * BN;
    unsigned short* C = h1c + (size_t)bx * BM * 4096 + bz * 512 + by * BN;

    const int wm = (wave >> 1) * 64, wn = (wave & 1) * 64;

    floatx4 acc[4][4] = {};

    for (int kt = 0; kt < 1024; kt += BK) {
#pragma unroll
      for (int i = 0; i < 4; i++)
        async_cp16(A + (size_t)(sr + 32 * i) * 1024 + kt + sc,
                   (char*)As + i * 4096 + tid * 16);
#pragma unroll
      for (int i = 0; i < 4; i++)
        async_cp16(Bt + (size_t)(sr + 32 * i) * 1024 + kt + sc,
                   (char*)Bs + i * 4096 + tid * 16);
      __syncthreads();
#pragma unroll
      for (int ks = 0; ks < 2; ks++) {
        short8 af[4], bf[4];
        const int ch = ((ks * 4 + lq) ^ sw) << 3;
#pragma unroll
        for (int i = 0; i < 4; i++)
          af[i] = *(const short8*)(As + (wm + 16 * i + lm) * BK + ch);
#pragma unroll
        for (int j = 0; j < 4; j++)
          bf[j] = *(const short8*)(Bs + (wn + 16 * j + lm) * BK + ch);
#pragma unroll
        for (int i = 0; i < 4; i++)
#pragma unroll
          for (int j = 0; j < 4; j++)
            acc[i][j] = __builtin_amdgcn_mfma_f32_16x16x32_bf16(af[i], bf[j], acc[i][j], 0, 0, 0);
      }
      __syncthreads();
    }

#pragma unroll
    for (int i = 0; i < 4; i++) {
      const int row = wm + 16 * i + lq * 4;
#pragma unroll
      for (int j = 0; j < 4; j++) {
        const int col = wn + 16 * j + lm;
        const float bv = bias[col];
#pragma unroll
        for (int v = 0; v < 4; v++) {
          float val = fmaxf(acc[i][j][v] + bv, 0.0f);
          C[(size_t)(row + v) * 4096 + col] = f32_to_bf16(val);
        }
      }
    }
  }
}

extern "C" void kernel_launch(void* const* d_in, const int* in_sizes, int n_in,
                              void* d_out, int out_size, void* d_ws, size_t ws_size,
                              hipStream_t stream) {
  (void)in_sizes; (void)n_in; (void)out_size;
  const float* x   = (const float*)d_in[0];
  const float* We1 = (const float*)d_in[1];
  const float* be1 = (const float*)d_in[2];
  const float* We2 = (const float*)d_in[3];
  const float* be2 = (const float*)d_in[4];
  const float* Wg  = (const float*)d_in[5];
  const float* bg  = (const float*)d_in[6];
  const float* Wt1 = (const float*)d_in[7];
  const float* bt1 = (const float*)d_in[8];
  const float* Wt2 = (const float*)d_in[9];
  const float* bt2 = (const float*)d_in[10];
  float* out = (float*)d_out;

  char* ws = (char*)d_ws;
  unsigned short* xb   = (unsigned short*)(ws + 0);            // 33,554,432
  unsigned short* W1T  = (unsigned short*)(ws + 33554432);     //  8,388,608
  unsigned short* W2T  = (unsigned short*)(ws + 41943040);     //  4,194,304
  unsigned short* Wt1T = (unsigned short*)(ws + 46137344);     //    786,432
  float*          gts  = (float*)(ws + 46923776);              //  1,572,864
  float*          WgT  = (float*)(ws + 48496640);              //     98,304
  const size_t fixed = 48594944;

  // Adaptive chunk size: per-chunk buffers need Bc*16384 bytes (h1c+eoc).
  size_t rem = ws_size > fixed ? ws_size - fixed : 0;
  int Bc = 16384;
  while (Bc > 512 && (size_t)Bc * 16384 > rem) Bc >>= 1;
  const int nc = 16384 / Bc;

  char* cb = ws + fixed;
  unsigned short* h1c = (unsigned short*)(cb);                      // Bc*8192 B
  unsigned short* eoc = (unsigned short*)(cb + (size_t)Bc * 8192);  // Bc*8192 B

  // --- prologue ---
  prep_kernel<<<dim3(16, 32, 20), dim3(32, 8), 0, stream>>>(We1, We2, Wt1, Wg, W1T, W2T, Wt1T, WgT);
  gates_cvt_kernel<<<4096, 256, 0, stream>>>(x, WgT, bg, gts, xb);

  // --- per-chunk pipeline: g1(0); for c: g2(c); merged{t(c)+g1(c+1)} | t(last) ---
  gemm_bt_relu<<<dim3(Bc / 128, 4, 8), 256, 0, stream>>>(
      xb, 0L, 1024, W1T, 524288L, be1, 512, h1c, 512L, 4096, 1024);
  for (int c = 0; c < nc; c++) {
    // eoc = relu(h1c @ We2 + be2)         M=Bc N=512 K=512 per expert
    gemm_bt_relu<<<dim3(Bc / 128, 4, 8), 256, 0, stream>>>(
        h1c, 512L, 4096, W2T, 262144L, be2, 512, eoc, 512L, 4096, 512);
    if (c < nc - 1) {
      const unsigned short* xbn = xb + (size_t)(c + 1) * Bc * 1024;
      const int TB = 3 * (Bc >> 6);
      const int GB = (Bc >> 7) * 32;
      tower_gemm1_kernel<<<TB + GB, 256, 0, stream>>>(
          eoc, gts, Wt1T, bt1, Wt2, bt2, out, c * Bc, Bc, xbn, W1T, be1, h1c);
    } else {
      tower_fused_kernel<<<3 * (Bc / 64), 256, 0, stream>>>(
          eoc, gts, Wt1T, bt1, Wt2, bt2, out, c * Bc, Bc);
    }
  }
}

// Round 8
// 483.522 us; speedup vs baseline: 1.0499x; 1.0499x over previous
//
#include <hip/hip_runtime.h>

// MMoE: B=16384, D=1024, E=8, H=512, T=256, TASKS=3
// R2: 701 us. R3: 593 us (coalesced gates). R4: 521 us (XOR-swizzle LDS).
// R5: 498 us fuse tail; 10 launches.
// R6/R7: 256x256 8-phase GEMM x2 attempts -> REGRESSED (92-98us @ 27-30% vs
//     128^2 84.6us @ 35%). Does not transfer to this shape. Reverted for good.
// R8: combine fused into tower A-staging -> 525us (serial chain exposed).
// R9: 489 us: T14 pipelining in tower (pv+B prefetch 1 iter ahead, Bs dbuf).
// R10: tower v3 counted-vmcnt -> 505 REGRESSED (m141 lesson). Reverted.
// R11: restore R9 -> 484.9 us BEST.
// R12: merge tower(c)+gemm1(c+1) heterogeneous kernel -> 507.6 REGRESSED:
//     merged dispatch 129.6us (> 84.5+18 separate), MfmaUtil 23.9%, FETCH 2x.
//     Slow single-buffered tower blocks dispatched FIRST occupy CUs; gemm1
//     tail serializes behind them; m114 co-scheduling is per-CU-wave, not
//     per-bimodal-block-distribution. Reverted.
// R13: final = R11 exactly. Ledger: GEMMs at m97-structure plateau (816 TF;
//     8-phase escape regressed 2x on this shape); tower T14-pipelined (2
//     alternatives regressed); ~155us residual fixed across launch configs.
//
// Workspace: fixed 48,594,944 B + Bc*16384 B chunk buffers (Bc adapts).

#define BM 128
#define BN 128
#define BK 64

typedef __attribute__((ext_vector_type(8))) short short8;
typedef __attribute__((ext_vector_type(4))) float floatx4;
typedef __attribute__((ext_vector_type(4))) unsigned short ushortx4;
typedef __attribute__((ext_vector_type(8))) unsigned short ushortx8;

__device__ __forceinline__ unsigned short f32_to_bf16(float f) {
  unsigned int u = __float_as_uint(f);
  u += 0x7fffu + ((u >> 16) & 1u);   // round-to-nearest-even (no NaNs in this net)
  return (unsigned short)(u >> 16);
}
__device__ __forceinline__ float bf16_to_f32(unsigned short h) {
  return __uint_as_float(((unsigned int)h) << 16);
}

__device__ __forceinline__ void async_cp16(const void* g, void* lds) {
  __builtin_amdgcn_global_load_lds(
      (const __attribute__((address_space(1))) void*)g,
      (__attribute__((address_space(3))) void*)lds, 16, 0, 0);
}

// ---------------- all weight prep in one kernel ----------------
// grid (16,32,20), block (32,8):
//   z 0..7  : We1 slice z  [1024][512] -> W1T  [512][1024] bf16
//   z 8..15 : We2 slice    [512][512]  -> W2T  [512][512]  bf16 (y<16)
//   z 16..18: Wt1 slice    [512][256]  -> Wt1T [256][512]  bf16 (x<8,y<16)
//   z 19    : Wg [3][1024][8] -> WgT [3][8][1024] fp32      (x<16,y<6)
__device__ __forceinline__ void transpose_slice(
    const float* __restrict__ in, unsigned short* __restrict__ out,
    int K, int N, float (*tile)[33]) {
  int n0 = blockIdx.x * 32, k0 = blockIdx.y * 32;
  for (int i = threadIdx.y; i < 32; i += 8)
    tile[i][threadIdx.x] = in[(size_t)(k0 + i) * N + n0 + threadIdx.x];
  __syncthreads();
  for (int i = threadIdx.y; i < 32; i += 8)
    out[(size_t)(n0 + i) * K + k0 + threadIdx.x] = f32_to_bf16(tile[threadIdx.x][i]);
}

__global__ void prep_kernel(const float* __restrict__ We1, const float* __restrict__ We2,
                            const float* __restrict__ Wt1, const float* __restrict__ Wg,
                            unsigned short* __restrict__ W1T, unsigned short* __restrict__ W2T,
                            unsigned short* __restrict__ Wt1T, float* __restrict__ WgT) {
  __shared__ float tile[32][33];
  int z = blockIdx.z;
  if (z < 8) {
    transpose_slice(We1 + (size_t)z * 524288, W1T + (size_t)z * 524288, 1024, 512, tile);
  } else if (z < 16) {
    if (blockIdx.y < 16)
      transpose_slice(We2 + (size_t)(z - 8) * 262144, W2T + (size_t)(z - 8) * 262144, 512, 512, tile);
  } else if (z < 19) {
    if (blockIdx.x < 8 && blockIdx.y < 16)
      transpose_slice(Wt1 + (size_t)(z - 16) * 131072, Wt1T + (size_t)(z - 16) * 131072, 512, 256, tile);
  } else {
    if (blockIdx.x < 16 && blockIdx.y < 6) {
      int idx = (blockIdx.y * 16 + blockIdx.x) * 256 + threadIdx.y * 32 + threadIdx.x;
      int t = idx >> 13, r = idx & 8191, e = r >> 10, d = r & 1023;
      WgT[idx] = Wg[t * 8192 + d * 8 + e];
    }
  }
}

// ---------------- gates + x->bf16 (fused; reads x once) ----------------
// WgT: [3][8][1024] fp32. One wave per batch row.
__global__ __launch_bounds__(256) void gates_cvt_kernel(
    const float* __restrict__ x, const float* __restrict__ WgT,
    const float* __restrict__ bg, float* __restrict__ gout,
    unsigned short* __restrict__ xb) {
  int wave = threadIdx.x >> 6, lane = threadIdx.x & 63;
  int b = blockIdx.x * 4 + wave;
  const float* xr = x + (size_t)b * 1024;
  float xv[16];
#pragma unroll
  for (int j = 0; j < 16; j++) xv[j] = xr[lane + 64 * j];
  unsigned short* xbr = xb + (size_t)b * 1024;
#pragma unroll
  for (int j = 0; j < 16; j++) xbr[lane + 64 * j] = f32_to_bf16(xv[j]);
  float mylogit = 0.f;
#pragma unroll
  for (int te = 0; te < 24; te++) {
    const float* w = WgT + te * 1024;
    float a = 0.f;
#pragma unroll
    for (int j = 0; j < 16; j++) a += xv[j] * w[lane + 64 * j];
#pragma unroll
    for (int off = 32; off > 0; off >>= 1) a += __shfl_xor(a, off, 64);
    if (lane == te) mylogit = a;   // compile-time te -> cndmask, no LDS
  }
  if (lane < 24) {   // groups of 8 (tasks) are 8-lane aligned; xor 4/2/1 stays in-group
    int t = lane >> 3, e = lane & 7;
    float logit = mylogit + bg[lane];
    float m = logit;
    m = fmaxf(m, __shfl_xor(m, 4, 64));
    m = fmaxf(m, __shfl_xor(m, 2, 64));
    m = fmaxf(m, __shfl_xor(m, 1, 64));
    float ex = __expf(logit - m);
    float s = ex;
    s += __shfl_xor(s, 4, 64);
    s += __shfl_xor(s, 2, 64);
    s += __shfl_xor(s, 1, 64);
    gout[(size_t)t * 131072 + (size_t)b * 8 + e] = ex / s;
  }
}

// ---------------- m97-style 128x128 bf16 GEMM (proven workhorse) ----------------
// C = relu(A * B^T + bias), bf16 out. LDS XOR-swizzled: slot (row, chunk c')
// holds global 16B-chunk c'^(row&7).
__global__ __launch_bounds__(256) void gemm_bt_relu(
    const unsigned short* __restrict__ Abase, long aOffZ, int lda,
    const unsigned short* __restrict__ Bbase, long bOffZ,
    const float* __restrict__ biasBase, int biasOffZ,
    unsigned short* __restrict__ Cbase, long cOffZ, int ldc,
    int K) {
  __shared__ __align__(16) unsigned short As[BM * BK];
  __shared__ __align__(16) unsigned short Bs[BN * BK];
  const int tid = threadIdx.x;
  const int z = blockIdx.z;
  const unsigned short* A = Abase + (size_t)aOffZ * z + (size_t)blockIdx.x * BM * lda;
  const unsigned short* Bt = Bbase + (size_t)bOffZ * z + (size_t)blockIdx.y * BN * K;
  const float* bias = biasBase + (size_t)biasOffZ * z + blockIdx.y * BN;
  unsigned short* C = Cbase + (size_t)cOffZ * z + (size_t)blockIdx.x * BM * ldc + blockIdx.y * BN;

  const int wave = tid >> 6, lane = tid & 63;
  const int wm = (wave >> 1) * 64, wn = (wave & 1) * 64;
  const int lm = lane & 15, lq = lane >> 4;
  const int sw = lm & 7;            // read-side swizzle key (= row & 7)

  floatx4 acc[4][4] = {};

  const int sr = tid >> 3;                               // staging row 0..31
  const int sc = (((tid & 7) ^ (sr & 7)) << 3);          // swizzled source col (elements)

  for (int kt = 0; kt < K; kt += BK) {
#pragma unroll
    for (int i = 0; i < 4; i++)
      async_cp16(A + (size_t)(sr + 32 * i) * lda + kt + sc,
                 (char*)As + i * 4096 + tid * 16);
#pragma unroll
    for (int i = 0; i < 4; i++)
      async_cp16(Bt + (size_t)(sr + 32 * i) * K + kt + sc,
                 (char*)Bs + i * 4096 + tid * 16);
    __syncthreads();   // drains vmcnt -> staged tiles visible
#pragma unroll
    for (int ks = 0; ks < 2; ks++) {
      short8 af[4], bf[4];
      const int ch = ((ks * 4 + lq) ^ sw) << 3;          // swizzled chunk (elements)
#pragma unroll
      for (int i = 0; i < 4; i++)
        af[i] = *(const short8*)(As + (wm + 16 * i + lm) * BK + ch);
#pragma unroll
      for (int j = 0; j < 4; j++)
        bf[j] = *(const short8*)(Bs + (wn + 16 * j + lm) * BK + ch);
#pragma unroll
      for (int i = 0; i < 4; i++)
#pragma unroll
        for (int j = 0; j < 4; j++)
          acc[i][j] = __builtin_amdgcn_mfma_f32_16x16x32_bf16(af[i], bf[j], acc[i][j], 0, 0, 0);
    }
    __syncthreads();   // protect LDS reuse next iter
  }

#pragma unroll
  for (int i = 0; i < 4; i++) {
    const int row = wm + 16 * i + lq * 4;
#pragma unroll
    for (int j = 0; j < 4; j++) {
      const int col = wn + 16 * j + lm;
      const float bv = bias[col];
#pragma unroll
      for (int v = 0; v < 4; v++) {
        float val = fmaxf(acc[i][j][v] + bv, 0.0f);
        C[(size_t)(row + v) * ldc + col] = f32_to_bf16(val);
      }
    }
  }
}

// ---------------- fused combine+towers, T14-pipelined (R9, measured best) ----------------
// preds = sigmoid(relu((sum_e g_te * eoc[:,e,:]) @ Wt1 + bt1) . Wt2 + bt2)
// 256 threads (4 waves), tile 64x256 (full tower width), K=512.
// pv (eoc regs) + next B-tile prefetched one iteration ahead; Bs double-
// buffered; end-of-iter barrier is a raw s_barrier (reads provably complete
// per-wave before arrival -> no vmcnt drain); only the top __syncthreads
// drains, and it drains iteration-old loads.
__global__ __launch_bounds__(256, 2) void tower_fused_kernel(
    const unsigned short* __restrict__ eoc, const float* __restrict__ gates,
    const unsigned short* __restrict__ Wt1T,
    const float* __restrict__ bt1, const float* __restrict__ Wt2,
    const float* __restrict__ bt2, float* __restrict__ out,
    int b0, int Bc) {
  __shared__ __align__(16) unsigned short As[64 * 64];      // 8 KB (reused for partials)
  __shared__ __align__(16) unsigned short Bs[2][256 * 64];  // 2 x 32 KB
  const int tid = threadIdx.x;
  const int mtiles = Bc >> 6;
  const int t = blockIdx.x / mtiles;            // task
  const int xbl = blockIdx.x % mtiles;          // m-tile within task
  const unsigned short* Bt = Wt1T + (size_t)t * 131072;

  const int wave = tid >> 6, lane = tid & 63;
  const int wn = wave * 64;
  const int lm = lane & 15, lq = lane >> 4;
  const int sw = lm & 7;
  const int sr = tid >> 3;                               // staging row 0..31
  const int sc = (((tid & 7) ^ (sr & 7)) << 3);          // (sr+32 has same key: 32&7==0)

  floatx4 acc[4][4] = {};

  // Gates for this thread's two staged rows (chunk-local rows sr, sr+32).
  float gv[2][8];
#pragma unroll
  for (int r = 0; r < 2; r++) {
    const floatx4* gp = (const floatx4*)(
        gates + ((size_t)t * 16384 + b0 + (size_t)xbl * 64 + sr + 32 * r) * 8);
    floatx4 g0 = gp[0], g1 = gp[1];
#pragma unroll
    for (int j = 0; j < 4; j++) { gv[r][j] = g0[j]; gv[r][4 + j] = g1[j]; }
  }

  const unsigned short* eb0 = eoc + ((size_t)(xbl * 64 + sr) * 8) * 512 + sc;
  const unsigned short* eb1 = eoc + ((size_t)(xbl * 64 + sr + 32) * 8) * 512 + sc;

  ushortx8 pv[2][8];   // prefetched eoc rows (2 staged rows x 8 experts)

#define STAGE_B_T(buf, kt_) do {                                             \
    _Pragma("unroll") for (int i_ = 0; i_ < 8; ++i_)                         \
      async_cp16(Bt + (size_t)(sr + 32 * i_) * 512 + (kt_) + sc,             \
                 (char*)Bs[buf] + i_ * 4096 + tid * 16); } while (0)

#define LOAD_PV(kt_) do {                                                    \
    _Pragma("unroll") for (int e_ = 0; e_ < 8; ++e_) {                       \
      pv[0][e_] = *(const ushortx8*)(eb0 + (size_t)e_ * 512 + (kt_));        \
      pv[1][e_] = *(const ushortx8*)(eb1 + (size_t)e_ * 512 + (kt_));        \
    } } while (0)

  STAGE_B_T(0, 0);
  LOAD_PV(0);

  for (int kt = 0; kt < 512; kt += 64) {
    const int cur = (kt >> 6) & 1;
    // fused combine for this kt (pv prefetched an iteration ago)
#pragma unroll
    for (int r = 0; r < 2; r++) {
      float s[8] = {};
#pragma unroll
      for (int e = 0; e < 8; e++) {
        const float g = gv[r][e];
#pragma unroll
        for (int j = 0; j < 8; j++) s[j] += g * bf16_to_f32(pv[r][e][j]);
      }
      ushortx8 o;
#pragma unroll
      for (int j = 0; j < 8; j++) o[j] = f32_to_bf16(s[j]);
      *(ushortx8*)((char*)As + r * 4096 + tid * 16) = o;   // swizzled slot
    }
    __syncthreads();   // As writes + Bs[cur] (staged one iter ago) visible
    if (kt < 448) {    // prefetch next iteration's inputs (consumed after next sync)
      STAGE_B_T(cur ^ 1, kt + 64);
      LOAD_PV(kt + 64);
    }
#pragma unroll
    for (int ks = 0; ks < 2; ks++) {
      short8 af[4], bf[4];
      const int ch = ((ks * 4 + lq) ^ sw) << 3;
#pragma unroll
      for (int i = 0; i < 4; i++)
        af[i] = *(const short8*)(As + (16 * i + lm) * 64 + ch);
#pragma unroll
      for (int j = 0; j < 4; j++)
        bf[j] = *(const short8*)(Bs[cur] + (wn + 16 * j + lm) * 64 + ch);
#pragma unroll
      for (int i = 0; i < 4; i++)
#pragma unroll
        for (int j = 0; j < 4; j++)
          acc[i][j] = __builtin_amdgcn_mfma_f32_16x16x32_bf16(af[i], bf[j], acc[i][j], 0, 0, 0);
    }
    // LDS-reuse barrier: raw (each wave's ds_reads completed before its MFMAs
    // via compiler lgkmcnt) -> no vmcnt(0) drain of the in-flight prefetches.
    __builtin_amdgcn_sched_barrier(0);
    __builtin_amdgcn_s_barrier();
    __builtin_amdgcn_sched_barrier(0);
  }

  // Epilogue: th = relu(acc + bt1[col]); partial[row] += th * Wt2[col]
  float b1v[4], w2v[4];
#pragma unroll
  for (int j = 0; j < 4; j++) {
    int col = wn + 16 * j + lm;
    b1v[j] = bt1[t * 256 + col];
    w2v[j] = Wt2[t * 256 + col];
  }
  float* pt = (float*)As;   // 64 rows x 4 wn-groups
#pragma unroll
  for (int i = 0; i < 4; i++) {
#pragma unroll
    for (int v = 0; v < 4; v++) {
      float p = 0.f;
#pragma unroll
      for (int j = 0; j < 4; j++)
        p += fmaxf(acc[i][j][v] + b1v[j], 0.0f) * w2v[j];
      p += __shfl_xor(p, 1, 64);
      p += __shfl_xor(p, 2, 64);
      p += __shfl_xor(p, 4, 64);
      p += __shfl_xor(p, 8, 64);
      if (lm == 0) pt[(16 * i + lq * 4 + v) * 4 + wave] = p;
    }
  }
  __syncthreads();
  if (tid < 64) {
    float s = pt[tid * 4] + pt[tid * 4 + 1] + pt[tid * 4 + 2] + pt[tid * 4 + 3] + bt2[t];
    out[(t << 14) + b0 + xbl * 64 + tid] = 1.f / (1.f + __expf(-s));
  }
}

extern "C" void kernel_launch(void* const* d_in, const int* in_sizes, int n_in,
                              void* d_out, int out_size, void* d_ws, size_t ws_size,
                              hipStream_t stream) {
  (void)in_sizes; (void)n_in; (void)out_size;
  const float* x   = (const float*)d_in[0];
  const float* We1 = (const float*)d_in[1];
  const float* be1 = (const float*)d_in[2];
  const float* We2 = (const float*)d_in[3];
  const float* be2 = (const float*)d_in[4];
  const float* Wg  = (const float*)d_in[5];
  const float* bg  = (const float*)d_in[6];
  const float* Wt1 = (const float*)d_in[7];
  const float* bt1 = (const float*)d_in[8];
  const float* Wt2 = (const float*)d_in[9];
  const float* bt2 = (const float*)d_in[10];
  float* out = (float*)d_out;

  char* ws = (char*)d_ws;
  unsigned short* xb   = (unsigned short*)(ws + 0);            // 33,554,432
  unsigned short* W1T  = (unsigned short*)(ws + 33554432);     //  8,388,608
  unsigned short* W2T  = (unsigned short*)(ws + 41943040);     //  4,194,304
  unsigned short* Wt1T = (unsigned short*)(ws + 46137344);     //    786,432
  float*          gts  = (float*)(ws + 46923776);              //  1,572,864
  float*          WgT  = (float*)(ws + 48496640);              //     98,304
  const size_t fixed = 48594944;

  // Adaptive chunk size: per-chunk buffers need Bc*16384 bytes (h1c+eoc).
  size_t rem = ws_size > fixed ? ws_size - fixed : 0;
  int Bc = 16384;
  while (Bc > 512 && (size_t)Bc * 16384 > rem) Bc >>= 1;
  const int nc = 16384 / Bc;

  char* cb = ws + fixed;
  unsigned short* h1c = (unsigned short*)(cb);                      // Bc*8192 B
  unsigned short* eoc = (unsigned short*)(cb + (size_t)Bc * 8192);  // Bc*8192 B

  // --- prologue ---
  prep_kernel<<<dim3(16, 32, 20), dim3(32, 8), 0, stream>>>(We1, We2, Wt1, Wg, W1T, W2T, Wt1T, WgT);
  gates_cvt_kernel<<<4096, 256, 0, stream>>>(x, WgT, bg, gts, xb);

  // --- per-chunk pipeline ---
  for (int c = 0; c < nc; c++) {
    const unsigned short* xbc = xb + (size_t)c * Bc * 1024;
    // h1c = relu(x_chunk @ We1 + be1)     M=Bc N=512 K=1024 per expert
    gemm_bt_relu<<<dim3(Bc / 128, 4, 8), 256, 0, stream>>>(
        xbc, 0L, 1024, W1T, 524288L, be1, 512, h1c, 512L, 4096, 1024);
    // eoc = relu(h1c @ We2 + be2)         M=Bc N=512 K=512 per expert
    gemm_bt_relu<<<dim3(Bc / 128, 4, 8), 256, 0, stream>>>(
        h1c, 512L, 4096, W2T, 262144L, be2, 512, eoc, 512L, 4096, 512);
    // preds = sigmoid(relu((sum_e g*eoc) @ Wt1 + bt1) . Wt2 + bt2)
    tower_fused_kernel<<<3 * (Bc / 64), 256, 0, stream>>>(
        eoc, gts, Wt1T, bt1, Wt2, bt2, out, c * Bc, Bc);
  }
}